// Round 6
// baseline (139.178 us; speedup 1.0000x reference)
//
#include <hip/hip_runtime.h>
#include <math.h>

#define THREADS 256
#define HW 2304

typedef __attribute__((ext_vector_type(8))) short short8;
typedef __attribute__((ext_vector_type(4))) float f32x4;
typedef __attribute__((ext_vector_type(8))) unsigned short us8;

typedef const __attribute__((address_space(1))) void* gas_p;
typedef __attribute__((address_space(3))) void* las_p;

__device__ __forceinline__ void gll16(const void* g, const void* l) {
    __builtin_amdgcn_global_load_lds((gas_p)g, (las_p)l, 16, 0, 0);
}

// ---- generic LDS staging: rows [rlo, rlo+rcount) of each channel, zero-padded,
//      row layout: 2 left-pad + W + 2 right-pad (rowfl = W+4, multiple of 4) ----
__device__ __forceinline__ void stage_rows(const float* __restrict__ src, float* __restrict__ dst,
                                           int nch, int chStride, int H, int W,
                                           int rlo, int rcount, int tid, int nthr, bool relu) {
    int rowfl = W + 4;
    int total = nch * rcount * rowfl;           // multiple of 4
    float4 z = make_float4(0.f, 0.f, 0.f, 0.f);
    for (int i = tid; i * 4 < total; i += nthr) ((float4*)dst)[i] = z;
    __syncthreads();
    int w2 = W >> 1;
    int m = nch * rcount * w2;
    for (int i = tid; i < m; i += nthr) {
        int c2 = i % w2;
        int rr = (i / w2) % rcount;
        int ch = i / (w2 * rcount);
        int srow = rlo + rr;
        if (srow < 0 || srow >= H) continue;
        float2 v = *(const float2*)(src + (size_t)ch * chStride + srow * W + 2 * c2);
        if (relu) { v.x = fmaxf(v.x, 0.f); v.y = fmaxf(v.y, 0.f); }
        *(float2*)(dst + (size_t)ch * rcount * rowfl + rr * rowfl + 2 + 2 * c2) = v;
    }
    __syncthreads();
}

#define LOAD_W9(wlbase, ci)                                        \
    const float4* wp4 = (const float4*)((wlbase) + (ci) * 12);     \
    float4 wa = wp4[0], wb = wp4[1], wc = wp4[2];                  \
    const float w9[9] = {wa.x, wa.y, wa.z, wa.w, wb.x, wb.y, wb.z, wb.w, wc.x};

// ---- embedding conv tail: given p9 taps, do conv(1->100) + norm + bf16 hi/lo split ----
__device__ __forceinline__ void emb_tail(const float* p9, int arr, int ni, int pix,
                                         unsigned short* __restrict__ hl, float* __restrict__ nrm,
                                         const float* wl) {
    float nsum = 0.f;
    char* rowp = (char*)(hl + (((size_t)(arr * 4 + ni)) * HW + pix) * 256);
    for (int g = 0; g < 16; ++g) {
        us8 vh, vl;
        #pragma unroll
        for (int j = 0; j < 8; ++j) {
            int e = g * 8 + j;
            float v = 0.f;
            if (e < 100) {
                v = wl[1200 + e];
                #pragma unroll
                for (int k = 0; k < 9; ++k) v = fmaf(p9[k], wl[e * 12 + k], v);
                nsum = fmaf(v, v, nsum);
            }
            unsigned bits = __float_as_uint(v);
            vh[j] = (unsigned short)(bits >> 16);
            float lo = v - __uint_as_float(bits & 0xFFFF0000u);
            vl[j] = (unsigned short)(__float_as_uint(lo) >> 16);
        }
        *(us8*)(rowp + g * 16) = vh;
        *(us8*)(rowp + 256 + g * 16) = vl;
    }
    nrm[(size_t)(arr * 4 + ni) * HW + pix] = nsum;
}

// ---- embedding conv body from a plain source plane ----
__device__ __forceinline__ void emb_body(const float* __restrict__ src, int arr, int ni, int pt,
                                         const float* __restrict__ ew, const float* __restrict__ eb,
                                         unsigned short* __restrict__ hl, float* __restrict__ nrm,
                                         float* wl, int tid, int nthr) {
    for (int i = tid; i < 900; i += nthr) wl[(i / 9) * 12 + (i % 9)] = ew[i];
    for (int i = tid; i < 100; i += nthr) wl[1200 + i] = eb[i];
    __syncthreads();

    int pix = pt * 256 + tid;
    int x = pix % 48, y = pix / 48;
    float p9[9];
    #pragma unroll
    for (int ky = 0; ky < 3; ++ky)
        #pragma unroll
        for (int kx = 0; kx < 3; ++kx) {
            int yy = y + ky - 1, xx = x + kx - 1;
            p9[ky * 3 + kx] = (yy >= 0 && yy < 48 && xx >= 0 && xx < 48) ? src[yy * 48 + xx] : 0.f;
        }
    emb_tail(p9, arr, ni, pix, hl, nrm, wl);
}

// ---- k_pre: d2b/d1b bias-init (float4), gmd/lmd inf-init, enc1pool. grid 158 ----
__global__ __launch_bounds__(256) void k_pre(
        float* __restrict__ d2b, float* __restrict__ d1b,
        const float* __restrict__ b2, const float* __restrict__ b1,
        unsigned* __restrict__ initbuf,
        const float* __restrict__ x3, const float* __restrict__ e1w,
        const float* __restrict__ e1b, float* __restrict__ e1u, float* __restrict__ p1) {
    __shared__ __align__(16) float lds[3 * 50 * 52];
    __shared__ __align__(16) float wl1[48];
    int bx = blockIdx.x;
    int tid = threadIdx.x;
    if (bx < 108) {
        int i4 = bx * 256 + tid;
        if (i4 < 9216) { int ch = (i4 / 144) & 31; float v = b2[ch]; ((float4*)d2b)[i4] = make_float4(v, v, v, v); }
        else { int j = i4 - 9216; int ch = (j / 576) & 15; float v = b1[ch]; ((float4*)d1b)[j] = make_float4(v, v, v, v); }
        return;
    }
    if (bx < 126) {
        int i = (bx - 108) * 256 + tid;        // 4608 uint4 over gmd+lmd
        uint4 f; f.x = f.y = f.z = f.w = 0x7F800000u;
        ((uint4*)initbuf)[i] = f;
        return;
    }
    // ---- enc1pool (32 blocks) ----
    int co = (bx - 126) & 15, n = (bx - 126) >> 4;
    for (int i = tid; i < 27; i += 256) wl1[(i / 9) * 12 + (i % 9)] = e1w[(co * 3) * 9 + i];
    stage_rows(x3 + (size_t)n * 3 * HW, lds, 3, HW, 48, 48, -1, 50, tid, 256, false);
    float bv = e1b[co];
    for (int o = 0; o < 3; ++o) {
        int po = o * 256 + tid;
        if (po >= 576) break;
        int py = po / 24, px = po % 24;
        float s[2][2] = {{bv, bv}, {bv, bv}};
        for (int ci = 0; ci < 3; ++ci) {
            const float* chp = lds + ci * 2600;
            float c[4][6];
            #pragma unroll
            for (int rr = 0; rr < 4; ++rr) {
                const float2* pr = (const float2*)(chp + (2 * py + rr) * 52);
                #pragma unroll
                for (int k = 0; k < 3; ++k) { float2 t = pr[px + k]; c[rr][2 * k] = t.x; c[rr][2 * k + 1] = t.y; }
            }
            LOAD_W9(wl1, ci)
            #pragma unroll
            for (int dy = 0; dy < 3; ++dy)
                #pragma unroll
                for (int dx = 0; dx < 3; ++dx) {
                    float wv = w9[dy * 3 + dx];
                    #pragma unroll
                    for (int yy = 0; yy < 2; ++yy)
                        #pragma unroll
                        for (int xx = 0; xx < 2; ++xx)
                            s[yy][xx] = fmaf(c[yy + dy][xx + dx + 1], wv, s[yy][xx]);
                }
        }
        float* ob = e1u + (size_t)(n * 16 + co) * HW;
        float mx = -INFINITY;
        #pragma unroll
        for (int yy = 0; yy < 2; ++yy)
            #pragma unroll
            for (int xx = 0; xx < 2; ++xx) {
                float v = fmaxf(s[yy][xx], 0.f);
                ob[(2 * py + yy) * 48 + 2 * px + xx] = v;
                mx = fmaxf(mx, v);
            }
        p1[(size_t)(n * 16 + co) * 576 + py * 24 + px] = mx;
    }
}

// ---- enc2pool (blocks 0..63) + embprep x1/arr0 (blocks 64..99). 256 threads ----
__global__ __launch_bounds__(256) void k_enc2pool(const float* __restrict__ p1, const float* __restrict__ w,
                                                  const float* __restrict__ b, float* __restrict__ e2,
                                                  float* __restrict__ p2,
                                                  const float* __restrict__ x1, const float* __restrict__ ew,
                                                  const float* __restrict__ eb,
                                                  unsigned short* __restrict__ hl, float* __restrict__ nrm) {
    __shared__ __align__(16) float smem[11840];
    int tid = threadIdx.x;
    if (blockIdx.x >= 64) {
        int sub = blockIdx.x - 64;
        int ni = sub / 9, pt = sub % 9;
        int plane = 2 + (ni & 1) + 4 * (ni >> 1);
        emb_body(x1 + (size_t)plane * HW, 0, ni, pt, ew, eb, hl, nrm, smem, tid, 256);
        return;
    }
    int co = blockIdx.x & 31, n = blockIdx.x >> 5;
    float* lds = smem;
    float* wl = smem + 11648;
    for (int i = tid; i < 144; i += 256) wl[(i / 9) * 12 + (i % 9)] = w[(co * 16) * 9 + i];
    stage_rows(p1 + (size_t)n * 16 * 576, lds, 16, 576, 24, 24, -1, 26, tid, 256, false);
    if (tid < 144) {
        int py = tid / 12, px = tid % 12;
        float bv = b[co];
        float s[2][2] = {{bv, bv}, {bv, bv}};
        for (int ci = 0; ci < 16; ++ci) {
            const float* chp = lds + ci * 728;
            float c[4][6];
            #pragma unroll
            for (int rr = 0; rr < 4; ++rr) {
                const float2* pr = (const float2*)(chp + (2 * py + rr) * 28);
                #pragma unroll
                for (int k = 0; k < 3; ++k) { float2 t = pr[px + k]; c[rr][2 * k] = t.x; c[rr][2 * k + 1] = t.y; }
            }
            LOAD_W9(wl, ci)
            #pragma unroll
            for (int dy = 0; dy < 3; ++dy)
                #pragma unroll
                for (int dx = 0; dx < 3; ++dx) {
                    float wv = w9[dy * 3 + dx];
                    #pragma unroll
                    for (int yy = 0; yy < 2; ++yy)
                        #pragma unroll
                        for (int xx = 0; xx < 2; ++xx)
                            s[yy][xx] = fmaf(c[yy + dy][xx + dx + 1], wv, s[yy][xx]);
                }
        }
        float* ob = e2 + (size_t)(n * 32 + co) * 576;
        float mx = -INFINITY;
        #pragma unroll
        for (int yy = 0; yy < 2; ++yy)
            #pragma unroll
            for (int xx = 0; xx < 2; ++xx) {
                float v = fmaxf(s[yy][xx], 0.f);
                ob[(2 * py + yy) * 24 + 2 * px + xx] = v;
                mx = fmaxf(mx, v);
            }
        p2[(size_t)(n * 32 + co) * 144 + py * 12 + px] = mx;
    }
}

// ---- bottleneck (blocks 0..127) + embprep x2/arr1 (blocks 128..163). 256 threads ----
__global__ __launch_bounds__(256) void k_bott(const float* __restrict__ p2, const float* __restrict__ w,
                                              const float* __restrict__ b, float* __restrict__ bt,
                                              const float* __restrict__ x2, const float* __restrict__ ew,
                                              const float* __restrict__ eb,
                                              unsigned short* __restrict__ hl, float* __restrict__ nrm) {
    __shared__ __align__(16) float smem[7552];
    int tid = threadIdx.x;
    if (blockIdx.x >= 128) {
        int sub = blockIdx.x - 128;
        int ni = sub / 9, pt = sub % 9;
        int plane = 2 + (ni & 1) + 4 * (ni >> 1);
        emb_body(x2 + (size_t)plane * HW, 1, ni, pt, ew, eb, hl, nrm, smem, tid, 256);
        return;
    }
    int co = blockIdx.x & 63, n = blockIdx.x >> 6;
    float* lds = smem;
    float* wl = smem + 7168;
    for (int i = tid; i < 288; i += 256) wl[(i / 9) * 12 + (i % 9)] = w[(co * 32) * 9 + i];
    stage_rows(p2 + (size_t)n * 32 * 144, lds, 32, 144, 12, 12, -1, 14, tid, 256, false);
    if (tid < 144) {
        int y = tid / 12, x = tid % 12;
        float acc = b[co];
        for (int ci = 0; ci < 32; ++ci) {
            const float* chp = lds + ci * 224;
            LOAD_W9(wl, ci)
            #pragma unroll
            for (int dy = 0; dy < 3; ++dy)
                #pragma unroll
                for (int dx = 0; dx < 3; ++dx)
                    acc = fmaf(chp[(y + dy) * 16 + x + dx + 1], w9[dy * 3 + dx], acc);
        }
        bt[(size_t)(n * 64 + co) * 144 + y * 12 + x] = fmaxf(acc, 0.f);
    }
}

// ---- dec2 partial: conv3x3 over concat(up(bt)[64], e2[32]); ci-chunked, atomicAdd ----
__global__ __launch_bounds__(192) void k_dec2p(const float* __restrict__ bt, const float* __restrict__ e2,
                                               const float* __restrict__ w, float* __restrict__ d2b) {
    int bx = blockIdx.x;
    int chunk = bx & 3, co = (bx >> 2) & 31, n = bx >> 7;
    int cib = chunk * 24;
    int nA = max(0, min(24, 64 - cib));
    int nB = 24 - nA;
    int tid = threadIdx.x;
    __shared__ __align__(16) float lds[24 * 26 * 28];
    __shared__ __align__(16) float wl[288];
    for (int i = tid; i < 216; i += 192) wl[(i / 9) * 12 + (i % 9)] = w[((size_t)co * 96 + cib) * 9 + i];
    stage_rows(bt + ((size_t)n * 64 + cib) * 144, lds, nA, 144, 12, 12, -1, 14, tid, 192, false);
    float* ldsB = lds + nA * 224;
    int e2c = max(0, cib + nA - 64);
    stage_rows(e2 + ((size_t)n * 32 + e2c) * 576, ldsB, nB, 576, 24, 24, -1, 26, tid, 192, false);
    if (tid < 144) {
        int y = tid / 6, qx = tid % 6;
        float acc[4] = {0.f, 0.f, 0.f, 0.f};
        int r0 = ((y - 1) >> 1) + 1;
        int yodd = y & 1;
        for (int ci = 0; ci < nA; ++ci) {
            const float* chp = lds + ci * 224;
            const float2* p0 = (const float2*)(chp + r0 * 16);
            const float2* p1 = (const float2*)(chp + (r0 + 1) * 16);
            float a0[6], a1[6], am[6];
            #pragma unroll
            for (int k = 0; k < 3; ++k) {
                float2 t0 = p0[qx + k], t1 = p1[qx + k];
                a0[2 * k] = t0.x; a0[2 * k + 1] = t0.y;
                a1[2 * k] = t1.x; a1[2 * k + 1] = t1.y;
            }
            #pragma unroll
            for (int k = 0; k < 6; ++k) am[k] = yodd ? a0[k] : a1[k];
            LOAD_W9(wl, ci)
            #pragma unroll
            for (int dy = 0; dy < 3; ++dy) {
                const float* rr = (dy == 0) ? a0 : (dy == 1 ? am : a1);
                #pragma unroll
                for (int dx = 0; dx < 3; ++dx) {
                    float wv = w9[dy * 3 + dx];
                    #pragma unroll
                    for (int j = 0; j < 4; ++j)
                        acc[j] = fmaf(rr[((j + dx - 1) >> 1) + 2], wv, acc[j]);
                }
            }
        }
        for (int ci = 0; ci < nB; ++ci) {
            const float* chp = ldsB + ci * 728;
            float bvv[3][8];
            #pragma unroll
            for (int r = 0; r < 3; ++r) {
                const float2* pr = (const float2*)(chp + (y + r) * 28);
                #pragma unroll
                for (int k = 0; k < 4; ++k) { float2 t = pr[2 * qx + k]; bvv[r][2 * k] = t.x; bvv[r][2 * k + 1] = t.y; }
            }
            LOAD_W9(wl, nA + ci)
            #pragma unroll
            for (int dy = 0; dy < 3; ++dy)
                #pragma unroll
                for (int dx = 0; dx < 3; ++dx) {
                    float wv = w9[dy * 3 + dx];
                    #pragma unroll
                    for (int j = 0; j < 4; ++j)
                        acc[j] = fmaf(bvv[dy][j + dx + 1], wv, acc[j]);
                }
        }
        float* op = d2b + ((size_t)(n * 32 + co)) * 576 + y * 24 + qx * 4;
        #pragma unroll
        for (int j = 0; j < 4; ++j) atomicAdd(op + j, acc[j]);
    }
}

// ---- dec1 partial: conv3x3 over concat(up(relu(d2b))[32], e1u[16]); atomicAdd ----
__global__ __launch_bounds__(192) void k_dec1p(const float* __restrict__ d2b, const float* __restrict__ e1u,
                                               const float* __restrict__ w, float* __restrict__ d1b) {
    int bx = blockIdx.x;
    int strip = bx % 3;
    int chunk = (bx / 3) & 3;
    int co = (bx / 12) & 15;
    int n = bx / 192;
    int cib = chunk * 12;
    int nA = max(0, min(12, 32 - cib));
    int nB = 12 - nA;
    int y0 = strip * 16;
    int yhlo = (y0 - 1) >> 1;
    int tid = threadIdx.x;
    __shared__ __align__(16) float lds[12 * 18 * 52];
    __shared__ __align__(16) float wl[144];
    for (int i = tid; i < 108; i += 192) wl[(i / 9) * 12 + (i % 9)] = w[((size_t)co * 48 + cib) * 9 + i];
    stage_rows(d2b + ((size_t)n * 32 + cib) * 576, lds, nA, 576, 24, 24, yhlo, 10, tid, 192, true);
    float* ldsB = lds + nA * 280;
    int e1c = max(0, cib + nA - 32);
    stage_rows(e1u + ((size_t)n * 16 + e1c) * HW, ldsB, nB, HW, 48, 48, y0 - 1, 18, tid, 192, false);
    {
        int yl = tid / 12, qx = tid % 12;
        int y = y0 + yl;
        float acc[4] = {0.f, 0.f, 0.f, 0.f};
        int r0 = ((y - 1) >> 1) - yhlo;
        int yodd = y & 1;
        for (int ci = 0; ci < nA; ++ci) {
            const float* chp = lds + ci * 280;
            const float2* p0 = (const float2*)(chp + r0 * 28);
            const float2* p1 = (const float2*)(chp + (r0 + 1) * 28);
            float a0[6], a1[6], am[6];
            #pragma unroll
            for (int k = 0; k < 3; ++k) {
                float2 t0 = p0[qx + k], t1 = p1[qx + k];
                a0[2 * k] = t0.x; a0[2 * k + 1] = t0.y;
                a1[2 * k] = t1.x; a1[2 * k + 1] = t1.y;
            }
            #pragma unroll
            for (int k = 0; k < 6; ++k) am[k] = yodd ? a0[k] : a1[k];
            LOAD_W9(wl, ci)
            #pragma unroll
            for (int dy = 0; dy < 3; ++dy) {
                const float* rr = (dy == 0) ? a0 : (dy == 1 ? am : a1);
                #pragma unroll
                for (int dx = 0; dx < 3; ++dx) {
                    float wv = w9[dy * 3 + dx];
                    #pragma unroll
                    for (int j = 0; j < 4; ++j)
                        acc[j] = fmaf(rr[((j + dx - 1) >> 1) + 2], wv, acc[j]);
                }
            }
        }
        for (int ci = 0; ci < nB; ++ci) {
            const float* chp = ldsB + ci * 936;
            float bvv[3][8];
            #pragma unroll
            for (int r = 0; r < 3; ++r) {
                const float2* pr = (const float2*)(chp + (yl + r) * 52);
                #pragma unroll
                for (int k = 0; k < 4; ++k) { float2 t = pr[2 * qx + k]; bvv[r][2 * k] = t.x; bvv[r][2 * k + 1] = t.y; }
            }
            LOAD_W9(wl, nA + ci)
            #pragma unroll
            for (int dy = 0; dy < 3; ++dy)
                #pragma unroll
                for (int dx = 0; dx < 3; ++dx) {
                    float wv = w9[dy * 3 + dx];
                    #pragma unroll
                    for (int j = 0; j < 4; ++j)
                        acc[j] = fmaf(bvv[dy][j + dx + 1], wv, acc[j]);
                }
        }
        float* op = d1b + ((size_t)(n * 16 + co)) * HW + y * 48 + qx * 4;
        #pragma unroll
        for (int j = 0; j < 4; ++j) atomicAdd(op + j, acc[j]);
    }
}

// ---- k_embout: emb3 directly from relu(d1b)*out_w (blocks 0..35) + out1x1 -> x3s (36..107) ----
__global__ __launch_bounds__(256) void k_embout(const float* __restrict__ d1b,
                                                const float* __restrict__ ow, const float* __restrict__ obias,
                                                const float* __restrict__ ew, const float* __restrict__ eb,
                                                unsigned short* __restrict__ hl, float* __restrict__ nrm,
                                                float* __restrict__ x3s) {
    __shared__ float wl[1300];
    int tid = threadIdx.x;
    if (blockIdx.x >= 36) {
        int idx = (blockIdx.x - 36) * 256 + tid;   // 18432
        int q = idx % HW;
        int co = (idx / HW) & 3;
        int n = idx / 9216;
        float acc = obias[co];
        #pragma unroll
        for (int ci = 0; ci < 16; ++ci)
            acc = fmaf(fmaxf(d1b[((size_t)(n * 16 + ci)) * HW + q], 0.f), ow[co * 16 + ci], acc);
        x3s[((size_t)(n * 4 + co)) * HW + q] = acc;
        return;
    }
    int ni = blockIdx.x / 9, pt = blockIdx.x % 9;
    int n = ni >> 1, co = 2 + (ni & 1);
    for (int i = tid; i < 900; i += 256) wl[(i / 9) * 12 + (i % 9)] = ew[i];
    for (int i = tid; i < 100; i += 256) wl[1200 + i] = eb[i];
    __syncthreads();

    float owr[16];
    #pragma unroll
    for (int k = 0; k < 16; ++k) owr[k] = ow[co * 16 + k];
    float ob = obias[co];
    const float* dp = d1b + (size_t)n * 16 * HW;

    int pix = pt * 256 + tid;
    int x = pix % 48, y = pix / 48;
    float p9[9];
    #pragma unroll
    for (int ky = 0; ky < 3; ++ky)
        #pragma unroll
        for (int kx = 0; kx < 3; ++kx) {
            int yy = y + ky - 1, xx = x + kx - 1;
            float v = 0.f;
            if (yy >= 0 && yy < 48 && xx >= 0 && xx < 48) {
                v = ob;
                int off = yy * 48 + xx;
                #pragma unroll
                for (int ci = 0; ci < 16; ++ci)
                    v = fmaf(fmaxf(dp[(size_t)ci * HW + off], 0.f), owr[ci], v);
            }
            p9[ky * 3 + kx] = v;
        }
    emb_tail(p9, 2, ni, pix, hl, nrm, wl);
}

// ================= global matching via split-bf16 MFMA, pipelined (verified r4) =================
#define NPC 24
__global__ __launch_bounds__(256, 2) void k_match(
        const unsigned short* __restrict__ hl, const float* __restrict__ nrm,
        unsigned* __restrict__ gmd, unsigned* __restrict__ lmd) {
    int bx = blockIdx.x;
    int l = (bx & 7) * 54 + (bx >> 3);        // bijective: 432 = 8*54
    int ps = l % 3;
    int qt = (l / 3) % 18;
    int mn = l / 54;
    int n = mn & 3;
    int m = mn >> 2;

    const unsigned short* curhl = hl + ((size_t)(8 + n)) * HW * 256;
    const unsigned short* refhl = hl + ((size_t)(m * 4 + n)) * HW * 256;
    const float* na = nrm + (size_t)(m * 4 + n) * HW;
    const float* nb = nrm + (size_t)(8 + n) * HW;
    unsigned* outd = (m == 0 ? gmd : lmd) + (size_t)n * HW;

    int qbase = qt * 128;
    int pbase = ps * 768;

    __shared__ __align__(16) unsigned short refl[2][32 * 256];   // 2 x 16 KB
    __shared__ __align__(16) float nal[768];                     // 3 KB

    int tid = threadIdx.x;
    int wave = tid >> 6;
    int lane = tid & 63;
    int lr = lane >> 5;
    int lc = lane & 31;

    if (tid < 192) *(float4*)&nal[tid * 4] = *(const float4*)(na + pbase + tid * 4);

    short8 ahi[2][4], alo[2][4];
    #pragma unroll
    for (int j = 0; j < 2; ++j) {
        int r = qbase + wave * 32 + j * 16 + (lane & 15);
        const unsigned short* rp = curhl + (size_t)r * 256;
        #pragma unroll
        for (int ks = 0; ks < 4; ++ks) {
            const unsigned short* p = rp + (ks * 4 + (lane >> 4)) * 8;
            ahi[j][ks] = *(const short8*)p;
            alo[j][ks] = *(const short8*)(p + 128);
        }
    }

    {
        const unsigned short* gb = refhl + (size_t)pbase * 256;
        #pragma unroll
        for (int t = 0; t < 4; ++t) {
            int i = wave * 4 + t;
            int r = 2 * i + lr;
            gll16(gb + (size_t)r * 256 + (lc ^ (r & 7)) * 8, &refl[0][i * 512]);
        }
    }
    asm volatile("s_waitcnt lgkmcnt(0)" ::: "memory");

    float dmin[2][4];
    #pragma unroll
    for (int j = 0; j < 2; ++j)
        #pragma unroll
        for (int r = 0; r < 4; ++r) dmin[j][r] = INFINITY;

    for (int pc = 0; pc < NPC; ++pc) {
        int cur = pc & 1;
        if (pc + 1 < NPC) {
            const unsigned short* gb = refhl + (size_t)(pbase + (pc + 1) * 32) * 256;
            #pragma unroll
            for (int t = 0; t < 4; ++t) {
                int i = wave * 4 + t;
                int r = 2 * i + lr;
                gll16(gb + (size_t)r * 256 + (lc ^ (r & 7)) * 8, &refl[cur ^ 1][i * 512]);
            }
            asm volatile("s_waitcnt vmcnt(4)" ::: "memory");
        } else {
            asm volatile("s_waitcnt vmcnt(0)" ::: "memory");
        }
        __builtin_amdgcn_s_barrier();

        short8 bhi[2][4], blo[2][4];
        #pragma unroll
        for (int ptile = 0; ptile < 2; ++ptile) {
            int r = ptile * 16 + (lane & 15);
            #pragma unroll
            for (int ks = 0; ks < 4; ++ks) {
                int cg = ks * 4 + (lane >> 4);
                const char* p = (const char*)refl[cur] + r * 512 + ((cg ^ (r & 7)) << 4);
                bhi[ptile][ks] = *(const short8*)p;
                blo[ptile][ks] = *(const short8*)(p + 256);
            }
        }

        f32x4 acc[2][2];
        #pragma unroll
        for (int ptile = 0; ptile < 2; ++ptile)
            #pragma unroll
            for (int j = 0; j < 2; ++j) acc[ptile][j] = (f32x4){0.f, 0.f, 0.f, 0.f};

        #pragma unroll
        for (int ks = 0; ks < 4; ++ks) {
            #pragma unroll
            for (int ptile = 0; ptile < 2; ++ptile)
                #pragma unroll
                for (int j = 0; j < 2; ++j)
                    acc[ptile][j] = __builtin_amdgcn_mfma_f32_16x16x32_bf16(
                        ahi[j][ks], bhi[ptile][ks], acc[ptile][j], 0, 0, 0);
            #pragma unroll
            for (int ptile = 0; ptile < 2; ++ptile)
                #pragma unroll
                for (int j = 0; j < 2; ++j)
                    acc[ptile][j] = __builtin_amdgcn_mfma_f32_16x16x32_bf16(
                        ahi[j][ks], blo[ptile][ks], acc[ptile][j], 0, 0, 0);
            #pragma unroll
            for (int ptile = 0; ptile < 2; ++ptile)
                #pragma unroll
                for (int j = 0; j < 2; ++j)
                    acc[ptile][j] = __builtin_amdgcn_mfma_f32_16x16x32_bf16(
                        alo[j][ks], bhi[ptile][ks], acc[ptile][j], 0, 0, 0);
        }

        #pragma unroll
        for (int ptile = 0; ptile < 2; ++ptile) {
            float nav = nal[pc * 32 + ptile * 16 + (lane & 15)];
            #pragma unroll
            for (int j = 0; j < 2; ++j)
                #pragma unroll
                for (int r = 0; r < 4; ++r)
                    dmin[j][r] = fminf(dmin[j][r], fmaf(-2.f, acc[ptile][j][r], nav));
        }
        __builtin_amdgcn_s_barrier();
    }

    #pragma unroll
    for (int j = 0; j < 2; ++j)
        #pragma unroll
        for (int r = 0; r < 4; ++r) {
            float v = dmin[j][r];
            v = fminf(v, __shfl_xor(v, 1, 64));
            v = fminf(v, __shfl_xor(v, 2, 64));
            v = fminf(v, __shfl_xor(v, 4, 64));
            v = fminf(v, __shfl_xor(v, 8, 64));
            if ((lane & 15) == 0) {
                int q = qbase + wave * 32 + j * 16 + 4 * (lane >> 4) + r;
                float d2 = fmaxf(v + nb[q], 0.f);
                atomicMin(&outd[q], __float_as_uint(d2));
            }
        }
}

// ============ final dsh conv (with inline distance->value map) ============
__global__ void k_final(const float* __restrict__ x3s, const unsigned* __restrict__ gmd,
                        const unsigned* __restrict__ lmd, const float* __restrict__ x2,
                        const float* __restrict__ dshw, const float* __restrict__ dshb,
                        float* __restrict__ out) {
    int idx = blockIdx.x * THREADS + threadIdx.x;
    if (idx >= 9216) return;
    int q = idx % HW, ni = idx / HW;
    int n = 2 + (ni & 1) + 4 * (ni >> 1);
    int b = ni >> 1;
    int x = q % 48, y = q / 48;
    float acc = dshb[0];
    for (int c = 0; c < 7; ++c) {
        const float* wp = dshw + c * 9;
        #pragma unroll
        for (int ky = 0; ky < 3; ++ky) {
            int yy = y + ky - 1;
            if (yy < 0 || yy >= 48) continue;
            #pragma unroll
            for (int kx = 0; kx < 3; ++kx) {
                int xx = x + kx - 1;
                if (xx < 0 || xx >= 48) continue;
                float v;
                if (c < 4) v = x3s[(size_t)(b * 4 + c) * HW + yy * 48 + xx];
                else if (c == 4) {
                    float d2 = __uint_as_float(gmd[(size_t)ni * HW + yy * 48 + xx]);
                    v = 1.f - 2.f / (1.f + expf(d2));
                } else if (c == 5) {
                    float d2 = __uint_as_float(lmd[(size_t)ni * HW + yy * 48 + xx]);
                    v = 1.f - 2.f / (1.f + expf(d2));
                } else v = x2[(size_t)n * HW + yy * 48 + xx];
                acc = fmaf(v, wp[ky * 3 + kx], acc);
            }
        }
    }
    out[idx] = acc;
}

extern "C" void kernel_launch(void* const* d_in, const int* in_sizes, int n_in,
                              void* d_out, int out_size, void* d_ws, size_t ws_size,
                              hipStream_t stream) {
    const float* x1     = (const float*)d_in[0];
    const float* x2     = (const float*)d_in[1];
    const float* x3     = (const float*)d_in[2];
    const float* enc1_w = (const float*)d_in[3];
    const float* enc1_b = (const float*)d_in[4];
    const float* enc2_w = (const float*)d_in[5];
    const float* enc2_b = (const float*)d_in[6];
    const float* bott_w = (const float*)d_in[7];
    const float* bott_b = (const float*)d_in[8];
    const float* dec2_w = (const float*)d_in[9];
    const float* dec2_b = (const float*)d_in[10];
    const float* dec1_w = (const float*)d_in[11];
    const float* dec1_b = (const float*)d_in[12];
    const float* out_w  = (const float*)d_in[13];
    const float* out_b  = (const float*)d_in[14];
    const float* emb_w  = (const float*)d_in[15];
    const float* emb_b  = (const float*)d_in[16];
    const float* dsh_w  = (const float*)d_in[17];
    const float* dsh_b  = (const float*)d_in[18];

    float* w = (float*)d_ws;
    float* e1u  = w;                   // 73728
    float* p1   = w + 73728;           // 18432
    float* e2   = w + 92160;           // 36864
    float* p2   = w + 129024;          // 9216
    float* bt   = w + 138240;          // 18432
    float* d2b  = w + 156672;          // 36864
    float* d1b  = w + 193536;          // 73728 (ends 267264)
    float* x3s  = w + 267264;          // 18432
    float* nrm  = w + 285696;          // 27648
    unsigned* gmd = (unsigned*)(w + 313344);   // 9216
    unsigned* lmd = (unsigned*)(w + 322560);   // 9216 (contiguous after gmd)
    unsigned short* hl = (unsigned short*)(w + 331776);  // 3*4*2304*256 ushorts

    k_pre<<<dim3(158), dim3(256), 0, stream>>>(d2b, d1b, dec2_b, dec1_b, gmd,
                                               x3, enc1_w, enc1_b, e1u, p1);
    k_enc2pool<<<dim3(100), dim3(256), 0, stream>>>(p1, enc2_w, enc2_b, e2, p2,
                                                    x1, emb_w, emb_b, hl, nrm);
    k_bott<<<dim3(164), dim3(256), 0, stream>>>(p2, bott_w, bott_b, bt,
                                                x2, emb_w, emb_b, hl, nrm);
    k_dec2p<<<dim3(256), dim3(192), 0, stream>>>(bt, e2, dec2_w, d2b);
    k_dec1p<<<dim3(384), dim3(192), 0, stream>>>(d2b, e1u, dec1_w, d1b);
    k_embout<<<dim3(108), dim3(256), 0, stream>>>(d1b, out_w, out_b, emb_w, emb_b, hl, nrm, x3s);
    k_match<<<dim3(432), dim3(256), 0, stream>>>(hl, nrm, gmd, lmd);
    k_final<<<dim3(36), dim3(THREADS), 0, stream>>>(x3s, gmd, lmd, x2, dsh_w, dsh_b, (float*)d_out);
}